// Round 9
// baseline (152.331 us; speedup 1.0000x reference)
//
#include <hip/hip_runtime.h>
#include <hip/hip_bf16.h>

#define MIN_NORM 1e-15f
#define EPS 1e-7f
#define MAX_NORM 1000.0f

#define NN 30000
#define PP 4
#define DD 64
#define EE 480000

typedef __attribute__((ext_vector_type(8))) short short8v;
typedef __attribute__((ext_vector_type(4))) float float4v;

__device__ inline float frcp(float x) { return __builtin_amdgcn_rcpf(x); }
__device__ inline float bf2f(unsigned short u) { return __uint_as_float(((unsigned)u) << 16); }
__device__ inline unsigned short f2bf(float f) {
    unsigned u = __float_as_uint(f);
    return (unsigned short)((u + 0x7fffu + ((u >> 16) & 1u)) >> 16);
}

// ---------- wave-wide helpers (bias stage only) ----------
__device__ inline float wsum(float v) {
#pragma unroll
    for (int off = 32; off >= 1; off >>= 1) v += __shfl_xor(v, off, 64);
    return v;
}
__device__ inline float expmap0_proj_pt(float v, int lane) {
    float sp = (lane == 0) ? 0.f : v;
    float n2 = wsum(sp * sp);
    float n = fmaxf(sqrtf(n2), MIN_NORM);
    float ep = __expf(n), em = frcp(ep);
    float s = 0.5f * (ep - em) * frcp(n);
    float time = sqrtf(fmaxf(1.f + s * s * n2, EPS));
    return (lane == 0) ? time : s * sp;
}
__device__ inline float logmap0_pt(float x, int lane) {
    float sp = (lane == 0) ? 0.f : x;
    float n2 = wsum(sp * sp);
    float n = fmaxf(sqrtf(n2), MIN_NORM);
    float x0 = __shfl(x, 0, 64);
    float th = fmaxf(x0, 1.f + EPS);
    float ac = __logf(th + sqrtf(fmaxf(th * th - 1.f, MIN_NORM)));
    return (lane == 0) ? 0.f : (ac * sp * frcp(n));
}
__device__ inline float gsum16(float v) {
#pragma unroll
    for (int off = 8; off >= 1; off >>= 1) v += __shfl_xor(v, off, 64);
    return v;
}
__device__ inline void gsum16x4(float& a, float& b, float& c, float& d) {
#pragma unroll
    for (int off = 8; off >= 1; off >>= 1) {
        a += __shfl_xor(a, off, 64);
        b += __shfl_xor(b, off, 64);
        c += __shfl_xor(c, off, 64);
        d += __shfl_xor(d, off, 64);
    }
}

// ---------- prep: pack W (MFMA B-frag order, split bf16 hi/lo) + zero counts/cursor ----------
__global__ void prep_kernel(const float* __restrict__ w,
                            unsigned short* __restrict__ bhi,
                            unsigned short* __restrict__ blo,
                            int* __restrict__ cz) {
    int b = blockIdx.x;
    if (b < 32) {
        int tt = b * 256 + threadIdx.x;  // [0, 8192)
        int lane = tt & 63;
        int ks = (tt >> 6) & 7;
        int nt = tt >> 9;
        int col = nt * 16 + (lane & 15);
        int kb = ks * 32 + (lane >> 4) * 8;
#pragma unroll
        for (int e = 0; e < 8; e++) {
            float v = w[col * 256 + kb + e];
            unsigned short h = f2bf(v);
            bhi[tt * 8 + e] = h;
            blo[tt * 8 + e] = f2bf(v - bf2f(h));
        }
    } else {
        int i = (b - 32) * 256 + threadIdx.x;
        if (i < 2 * NN) cz[i] = 0;
    }
}

// ---------- fused front (GR=16) + fire-and-forget edge histogram (1 edge/thread) ----------
#define GR 16
#define UPITCH 264            // bf16 elems per row (528 B)
__global__ __launch_bounds__(256) void fused_front_hist_kernel(const float* __restrict__ x,
                                                               const unsigned short* __restrict__ bhi,
                                                               const unsigned short* __restrict__ blo,
                                                               const float* __restrict__ bias,
                                                               unsigned short* __restrict__ xt,
                                                               const int* __restrict__ adj_row,
                                                               int* __restrict__ counts) {
    __shared__ __align__(16) char smem[17952];
    unsigned short* uh = (unsigned short*)smem;            // [16][264] bf16 hi
    unsigned short* ul = (unsigned short*)(smem + 8448);   // [16][264] bf16 lo
    float* uspL = (float*)(smem + 16896);                  // [256] bias tangent
    float* u2L  = (float*)(smem + 17920);                  // [4] ||usp||^2 per point

    int tid = threadIdx.x;
    int lane = tid & 63;
    int wv = tid >> 6;
    int row0 = blockIdx.x * GR;

    // ---- fire-and-forget histogram: 1875 blocks x 256 threads = 480000 edges ----
    atomicAdd(&counts[adj_row[blockIdx.x * 256 + tid]], 1);

    // ---- bias tangent (wave wv == point wv), staged to LDS ----
    {
        float b = bias[wv * 64 + lane];
        float y = expmap0_proj_pt(b, lane);
        float usp = logmap0_pt(y, lane);
        float U2 = wsum(usp * usp);
        uspL[wv * 64 + lane] = usp;
        if (lane == 0) u2L[wv] = U2;
    }

    // ---- prologue (transposed): thread (r = tid>>4, l = tid&15) ----
    int r = tid >> 4, l = tid & 15;
    {
        const float4* xr = (const float4*)(x + (size_t)(row0 + r) * 256);
        float4 a[4];
#pragma unroll
        for (int p = 0; p < 4; p++) a[p] = xr[p * 16 + l];
        float s0, s1, s2, s3;
        {
            float m0 = (l == 0) ? 0.f : a[0].x;
            float m1 = (l == 0) ? 0.f : a[1].x;
            float m2 = (l == 0) ? 0.f : a[2].x;
            float m3 = (l == 0) ? 0.f : a[3].x;
            s0 = m0 * m0 + a[0].y * a[0].y + a[0].z * a[0].z + a[0].w * a[0].w;
            s1 = m1 * m1 + a[1].y * a[1].y + a[1].z * a[1].z + a[1].w * a[1].w;
            s2 = m2 * m2 + a[2].y * a[2].y + a[2].z * a[2].z + a[2].w * a[2].w;
            s3 = m3 * m3 + a[3].y * a[3].y + a[3].z * a[3].z + a[3].w * a[3].w;
        }
        gsum16x4(s0, s1, s2, s3);
        float n2a[4] = {s0, s1, s2, s3};
#pragma unroll
        for (int p = 0; p < 4; p++) {
            float n2 = n2a[p];
            float n = fmaxf(sqrtf(n2), MIN_NORM);
            float th = fmaxf(sqrtf(1.f + n2), 1.f + EPS);
            float ac = __logf(th + sqrtf(fmaxf(th * th - 1.f, MIN_NORM)));
            float sc = ac * frcp(n);
            float ux0 = (l == 0) ? 0.f : sc * a[p].x;
            float uy = sc * a[p].y, uz = sc * a[p].z, uw = sc * a[p].w;
            unsigned short hx = f2bf(ux0), hy = f2bf(uy), hz = f2bf(uz), hw = f2bf(uw);
            ushort4 hv = {hx, hy, hz, hw};
            ushort4 lv = {f2bf(ux0 - bf2f(hx)), f2bf(uy - bf2f(hy)),
                          f2bf(uz - bf2f(hz)), f2bf(uw - bf2f(hw))};
            *(ushort4*)(uh + r * UPITCH + p * 64 + 4 * l) = hv;
            *(ushort4*)(ul + r * UPITCH + p * 64 + 4 * l) = lv;
        }
    }
    __syncthreads();  // the only barrier

    // ---- MFMA GEMM: M=16, N=256 (wave wv: 4 n-tiles), K=256, split-bf16 3-term ----
    float4v acc[4];
#pragma unroll
    for (int j = 0; j < 4; j++) acc[j] = (float4v){0.f, 0.f, 0.f, 0.f};
    int abyte = (lane & 15) * (UPITCH * 2) + (lane >> 4) * 16;
#pragma unroll
    for (int ks = 0; ks < 8; ks++) {
        short8v Ah = *(const short8v*)(smem + abyte + ks * 64);
        short8v Al = *(const short8v*)(smem + 8448 + abyte + ks * 64);
#pragma unroll
        for (int j = 0; j < 4; j++) {
            size_t chunk = ((size_t)((wv * 4 + j) * 8 + ks) * 64 + lane) * 8;
            short8v Bh = *(const short8v*)(bhi + chunk);
            short8v Bl = *(const short8v*)(blo + chunk);
            acc[j] = __builtin_amdgcn_mfma_f32_16x16x32_bf16(Ah, Bh, acc[j], 0, 0, 0);
            acc[j] = __builtin_amdgcn_mfma_f32_16x16x32_bf16(Al, Bh, acc[j], 0, 0, 0);
            acc[j] = __builtin_amdgcn_mfma_f32_16x16x32_bf16(Ah, Bl, acc[j], 0, 0, 0);
        }
    }

    // ---- epilogue directly from accumulators ----
    // D layout: col = (wv*4+j)*16 + (lane&15), row = (lane>>4)*4 + reg
    int lp = lane & 15, hi = lane >> 4;
    float uf[4];
#pragma unroll
    for (int j = 0; j < 4; j++) uf[j] = uspL[wv * 64 + j * 16 + lp];
    if (lp == 0) {  // mask the point's time element (global col d=0 -> j==0, lp==0)
        acc[0][0] = 0.f; acc[0][1] = 0.f; acc[0][2] = 0.f; acc[0][3] = 0.f;
    }
    float n2v[4], duv[4];
#pragma unroll
    for (int reg = 0; reg < 4; reg++) {
        float pn = 0.f, pd = 0.f;
#pragma unroll
        for (int j = 0; j < 4; j++) {
            pn = fmaf(acc[j][reg], acc[j][reg], pn);
            pd = fmaf(acc[j][reg], uf[j], pd);
        }
        n2v[reg] = pn; duv[reg] = pd;
    }
#pragma unroll
    for (int off = 1; off < 16; off <<= 1) {
#pragma unroll
        for (int reg = 0; reg < 4; reg++) {
            n2v[reg] += __shfl_xor(n2v[reg], off, 64);
            duv[reg] += __shfl_xor(duv[reg], off, 64);
        }
    }
    float U2 = u2L[wv];

    float A[4], Bc[4];
#pragma unroll
    for (int reg = 0; reg < 4; reg++) {
        float n2 = n2v[reg], duu = duv[reg];
        float n = fmaxf(sqrtf(n2), MIN_NORM);
        float epv = __expf(n), emv = frcp(epv);
        float sv = 0.5f * (epv - emv) * frcp(n);     // sinh(n)/n
        float hs2 = sv * sv * n2;
        float h0 = sqrtf(fmaxf(1.f + hs2, EPS));
        float yn = fmaxf(sv * n, MIN_NORM);
        float dhu = sv * duu;
        float alpha = dhu * frcp(yn);
        float g = alpha * (1.f - h0);
        float ux = dhu - g * yn;
        float t = ux * frcp(fmaxf(h0, MIN_NORM));
        float w2 = U2 - 2.f * g * alpha + g * g;
        float md = w2 - t * t;
        float normu = fminf(sqrtf(fmaxf(md, EPS)), MAX_NORM);
        float theta = fmaxf(normu, MIN_NORM);
        float ep2 = __expf(theta), em2 = frcp(ep2);
        float ch = 0.5f * (ep2 + em2);
        float shot = 0.5f * (ep2 - em2) * frcp(theta);
        float rn2 = ch * ch * hs2 + 2.f * ch * shot * ux + shot * shot * w2;
        float rtime = sqrtf(fmaxf(1.f + rn2, EPS));
        float th2 = fmaxf(rtime, 1.f + EPS);
        float ac2 = __logf(th2 + sqrtf(fmaxf(th2 * th2 - 1.f, MIN_NORM)));
        float rn = fmaxf(sqrtf(rn2), MIN_NORM);
        float K = ac2 * frcp(rn);
        A[reg] = K * sv * (ch - shot * g * frcp(yn));
        Bc[reg] = K * shot;
    }

    unsigned short* xbase = xt + (size_t)(row0 + hi * 4) * 256 + wv * 64 + lp;
#pragma unroll
    for (int reg = 0; reg < 4; reg++) {
#pragma unroll
        for (int j = 0; j < 4; j++) {
            float o = fmaf(A[reg], acc[j][reg], Bc[reg] * uf[j]);
            xbase[reg * 256 + j * 16] = f2bf(o);
        }
    }
}

// ---------- scan (single block, int4 loads) ----------
#define SCH 32
__global__ __launch_bounds__(1024) void scan_kernel(const int* __restrict__ counts,
                                                    int* __restrict__ starts, int n) {
    int tid = threadIdx.x, lane = tid & 63, wv = tid >> 6;
    int i0 = tid * SCH;
    int c[SCH];
    const int4* c4 = (const int4*)(counts + i0);
#pragma unroll
    for (int q = 0; q < 8; q++) {
        int4 v = c4[q];   // reads past n land in zeroed cursor region (safe, zero)
        c[4 * q] = v.x; c[4 * q + 1] = v.y; c[4 * q + 2] = v.z; c[4 * q + 3] = v.w;
    }
    int s = 0;
#pragma unroll
    for (int j = 0; j < SCH; j++) s += c[j];
    int incl = s;
#pragma unroll
    for (int off = 1; off < 64; off <<= 1) {
        int t = __shfl_up(incl, off, 64);
        if (lane >= off) incl += t;
    }
    __shared__ int wtot[16];
    if (lane == 63) wtot[wv] = incl;
    __syncthreads();
    if (wv == 0 && lane < 16) {
        int v = wtot[lane];
        int sc = v;
#pragma unroll
        for (int off = 1; off < 16; off <<= 1) {
            int t = __shfl_up(sc, off, 64);
            if (lane >= off) sc += t;
        }
        wtot[lane] = sc - v;  // exclusive
    }
    __syncthreads();
    int run = incl - s + wtot[wv];
#pragma unroll
    for (int j = 0; j < SCH; j++) {
        int idx = i0 + j;
        if (idx < n) starts[idx] = run;
        run += c[j];
    }
    if (tid == 1023) starts[n] = run;
}

// ---------- scatter: packed (col, val) per edge ----------
__global__ void scatter_kernel(const int* __restrict__ row, const int* __restrict__ col,
                               const float* __restrict__ val, const int* __restrict__ starts,
                               int* __restrict__ cursor, int2* __restrict__ ep, int E) {
    int e = blockIdx.x * 256 + threadIdx.x;
    if (e < E) {
        int r = row[e];
        int pos = starts[r] + atomicAdd(&cursor[r], 1);
        ep[pos] = make_int2(col[e], __float_as_int(val[e]));
    }
}

// ---------- SpMM (wave/row, predicated 16-wide batches) + fused final chain ----------
__global__ __launch_bounds__(256) void spmm_final_kernel(const unsigned short* __restrict__ xt,
                                                         const int2* __restrict__ ep,
                                                         const int* __restrict__ starts,
                                                         float4* __restrict__ out4) {
    int w = threadIdx.x >> 6;
    int lane = threadIdx.x & 63;
    int r = blockIdx.x * 4 + w;
    int s = starts[r], e = starts[r + 1];

    float4 acc = {0.f, 0.f, 0.f, 0.f};
    for (int i = s; i < e; i += 16) {
        int cs[16]; float vs[16];
#pragma unroll
        for (int u = 0; u < 16; u++) {
            int idx = i + u;
            bool ok = idx < e;
            int2 pe = ep[ok ? idx : s];
            cs[u] = pe.x;
            vs[u] = ok ? __int_as_float(pe.y) : 0.f;
        }
        ushort4 av[16];
#pragma unroll
        for (int u = 0; u < 16; u++)
            av[u] = *(const ushort4*)(xt + ((size_t)cs[u] << 8) + (lane << 2));
#pragma unroll
        for (int u = 0; u < 16; u++) {
            acc.x = fmaf(vs[u], bf2f(av[u].x), acc.x);
            acc.y = fmaf(vs[u], bf2f(av[u].y), acc.y);
            acc.z = fmaf(vs[u], bf2f(av[u].z), acc.z);
            acc.w = fmaf(vs[u], bf2f(av[u].w), acc.w);
        }
    }

    acc.x = fminf(acc.x, MAX_NORM); acc.y = fminf(acc.y, MAX_NORM);
    acc.z = fminf(acc.z, MAX_NORM); acc.w = fminf(acc.w, MAX_NORM);

    // final chain: expmap0+proj -> logmap0 -> relu/clamp -> expmap0+proj
    bool leader = ((lane & 15) == 0);
    float4 sp = acc;
    if (leader) sp.x = 0.f;
    float n2 = gsum16(sp.x * sp.x + sp.y * sp.y + sp.z * sp.z + sp.w * sp.w);
    float n = fmaxf(sqrtf(n2), MIN_NORM);
    float ep1 = __expf(n), em1 = frcp(ep1);
    float s1 = 0.5f * (ep1 - em1) * frcp(n);
    float hs2 = s1 * s1 * n2;
    float time = sqrtf(fmaxf(1.f + hs2, EPS));
    float th = fmaxf(time, 1.f + EPS);
    float ac = __logf(th + sqrtf(fmaxf(th * th - 1.f, MIN_NORM)));
    float hn = fmaxf(s1 * n, MIN_NORM);
    float sc = ac * s1 * frcp(hn);
    float4 t;
    t.x = leader ? 0.f : sc * sp.x;
    t.y = sc * sp.y;
    t.z = sc * sp.z;
    t.w = sc * sp.w;
    t.x = fminf(fmaxf(t.x, 0.f), MAX_NORM);
    t.y = fminf(fmaxf(t.y, 0.f), MAX_NORM);
    t.z = fminf(fmaxf(t.z, 0.f), MAX_NORM);
    t.w = fminf(fmaxf(t.w, 0.f), MAX_NORM);
    float t2 = gsum16(t.x * t.x + t.y * t.y + t.z * t.z + t.w * t.w);
    float nt = fmaxf(sqrtf(t2), MIN_NORM);
    float ep3 = __expf(nt), em3 = frcp(ep3);
    float s3 = 0.5f * (ep3 - em3) * frcp(nt);
    float time3 = sqrtf(fmaxf(1.f + s3 * s3 * t2, EPS));
    float4 o;
    o.x = leader ? time3 : s3 * t.x;
    o.y = s3 * t.y;
    o.z = s3 * t.z;
    o.w = s3 * t.w;

    out4[(size_t)r * 64 + lane] = o;
}

extern "C" void kernel_launch(void* const* d_in, const int* in_sizes, int n_in,
                              void* d_out, int out_size, void* d_ws, size_t ws_size,
                              hipStream_t stream) {
    const float* x       = (const float*)d_in[0];
    const float* adj_val = (const float*)d_in[1];
    const float* weight  = (const float*)d_in[2];
    const float* bias    = (const float*)d_in[3];
    const int*   adj_row = (const int*)d_in[4];
    const int*   adj_col = (const int*)d_in[5];

    const int N = NN, E = EE;

    unsigned short* B   = (unsigned short*)d_ws;          // N*256 bf16 (xt)
    unsigned short* Whi = B + (size_t)N * 256;            // 65536 ushort
    unsigned short* Wlo = Whi + 65536;                    // 65536 ushort
    int* counts  = (int*)(Wlo + 65536);                   // N   (16B-aligned)
    int* cursor  = counts + N;                            // N
    int* starts  = cursor + N;                            // N+1 (+1 pad for int2 align)
    int2* ep     = (int2*)(starts + N + 2);               // E   (8B-aligned)

    prep_kernel<<<32 + (2 * N + 255) / 256, 256, 0, stream>>>(weight, Whi, Wlo, counts);
    fused_front_hist_kernel<<<N / GR, 256, 0, stream>>>(x, Whi, Wlo, bias, B,
                                                        adj_row, counts);
    scan_kernel<<<1, 1024, 0, stream>>>(counts, starts, N);
    scatter_kernel<<<(E + 255) / 256, 256, 0, stream>>>(adj_row, adj_col, adj_val,
                                                        starts, cursor, ep, E);
    spmm_final_kernel<<<N / 4, 256, 0, stream>>>(B, ep, starts, (float4*)d_out);
}

// Round 10
// 149.867 us; speedup vs baseline: 1.0164x; 1.0164x over previous
//
#include <hip/hip_runtime.h>
#include <hip/hip_bf16.h>

#define MIN_NORM 1e-15f
#define EPS 1e-7f
#define MAX_NORM 1000.0f

#define NN 30000
#define PP 4
#define DD 64
#define EE 480000

typedef __attribute__((ext_vector_type(8))) short short8v;
typedef __attribute__((ext_vector_type(4))) float float4v;

__device__ inline float frcp(float x) { return __builtin_amdgcn_rcpf(x); }
__device__ inline float bf2f(unsigned short u) { return __uint_as_float(((unsigned)u) << 16); }
__device__ inline unsigned short f2bf(float f) {
    unsigned u = __float_as_uint(f);
    return (unsigned short)((u + 0x7fffu + ((u >> 16) & 1u)) >> 16);
}

// ---------- wave-wide helpers (bias stage only) ----------
__device__ inline float wsum(float v) {
#pragma unroll
    for (int off = 32; off >= 1; off >>= 1) v += __shfl_xor(v, off, 64);
    return v;
}
__device__ inline float expmap0_proj_pt(float v, int lane) {
    float sp = (lane == 0) ? 0.f : v;
    float n2 = wsum(sp * sp);
    float n = fmaxf(sqrtf(n2), MIN_NORM);
    float ep = __expf(n), em = frcp(ep);
    float s = 0.5f * (ep - em) * frcp(n);
    float time = sqrtf(fmaxf(1.f + s * s * n2, EPS));
    return (lane == 0) ? time : s * sp;
}
__device__ inline float logmap0_pt(float x, int lane) {
    float sp = (lane == 0) ? 0.f : x;
    float n2 = wsum(sp * sp);
    float n = fmaxf(sqrtf(n2), MIN_NORM);
    float x0 = __shfl(x, 0, 64);
    float th = fmaxf(x0, 1.f + EPS);
    float ac = __logf(th + sqrtf(fmaxf(th * th - 1.f, MIN_NORM)));
    return (lane == 0) ? 0.f : (ac * sp * frcp(n));
}
__device__ inline float gsum16(float v) {
#pragma unroll
    for (int off = 8; off >= 1; off >>= 1) v += __shfl_xor(v, off, 64);
    return v;
}
__device__ inline void gsum16x4(float& a, float& b, float& c, float& d) {
#pragma unroll
    for (int off = 8; off >= 1; off >>= 1) {
        a += __shfl_xor(a, off, 64);
        b += __shfl_xor(b, off, 64);
        c += __shfl_xor(c, off, 64);
        d += __shfl_xor(d, off, 64);
    }
}

// ---------- prep: pack W into MFMA B-frag order, split bf16 hi/lo ----------
__global__ void prep_kernel(const float* __restrict__ w,
                            unsigned short* __restrict__ bhi,
                            unsigned short* __restrict__ blo) {
    int tt = blockIdx.x * 256 + threadIdx.x;  // [0, 8192)
    int lane = tt & 63;
    int ks = (tt >> 6) & 7;
    int nt = tt >> 9;
    int col = nt * 16 + (lane & 15);
    int kb = ks * 32 + (lane >> 4) * 8;
#pragma unroll
    for (int e = 0; e < 8; e++) {
        float v = w[col * 256 + kb + e];
        unsigned short h = f2bf(v);
        bhi[tt * 8 + e] = h;
        blo[tt * 8 + e] = f2bf(v - bf2f(h));
    }
}

// ---------- fused front (GR=16) + fire-and-forget edge histogram (1 edge/thread) ----------
#define GR 16
#define UPITCH 264            // bf16 elems per row (528 B)
__global__ __launch_bounds__(256) void fused_front_hist_kernel(const float* __restrict__ x,
                                                               const unsigned short* __restrict__ bhi,
                                                               const unsigned short* __restrict__ blo,
                                                               const float* __restrict__ bias,
                                                               unsigned short* __restrict__ xt,
                                                               const int* __restrict__ adj_row,
                                                               int* __restrict__ counts) {
    __shared__ __align__(16) char smem[17952];
    unsigned short* uh = (unsigned short*)smem;            // [16][264] bf16 hi
    unsigned short* ul = (unsigned short*)(smem + 8448);   // [16][264] bf16 lo
    float* uspL = (float*)(smem + 16896);                  // [256] bias tangent
    float* u2L  = (float*)(smem + 17920);                  // [4] ||usp||^2 per point

    int tid = threadIdx.x;
    int lane = tid & 63;
    int wv = tid >> 6;
    int row0 = blockIdx.x * GR;

    // ---- fire-and-forget histogram: 1875 blocks x 256 threads = 480000 edges ----
    atomicAdd(&counts[adj_row[blockIdx.x * 256 + tid]], 1);

    // ---- bias tangent (wave wv == point wv), staged to LDS ----
    {
        float b = bias[wv * 64 + lane];
        float y = expmap0_proj_pt(b, lane);
        float usp = logmap0_pt(y, lane);
        float U2 = wsum(usp * usp);
        uspL[wv * 64 + lane] = usp;
        if (lane == 0) u2L[wv] = U2;
    }

    // ---- prologue (transposed): thread (r = tid>>4, l = tid&15) ----
    int r = tid >> 4, l = tid & 15;
    {
        const float4* xr = (const float4*)(x + (size_t)(row0 + r) * 256);
        float4 a[4];
#pragma unroll
        for (int p = 0; p < 4; p++) a[p] = xr[p * 16 + l];
        float s0, s1, s2, s3;
        {
            float m0 = (l == 0) ? 0.f : a[0].x;
            float m1 = (l == 0) ? 0.f : a[1].x;
            float m2 = (l == 0) ? 0.f : a[2].x;
            float m3 = (l == 0) ? 0.f : a[3].x;
            s0 = m0 * m0 + a[0].y * a[0].y + a[0].z * a[0].z + a[0].w * a[0].w;
            s1 = m1 * m1 + a[1].y * a[1].y + a[1].z * a[1].z + a[1].w * a[1].w;
            s2 = m2 * m2 + a[2].y * a[2].y + a[2].z * a[2].z + a[2].w * a[2].w;
            s3 = m3 * m3 + a[3].y * a[3].y + a[3].z * a[3].z + a[3].w * a[3].w;
        }
        gsum16x4(s0, s1, s2, s3);
        float n2a[4] = {s0, s1, s2, s3};
#pragma unroll
        for (int p = 0; p < 4; p++) {
            float n2 = n2a[p];
            float n = fmaxf(sqrtf(n2), MIN_NORM);
            float th = fmaxf(sqrtf(1.f + n2), 1.f + EPS);
            float ac = __logf(th + sqrtf(fmaxf(th * th - 1.f, MIN_NORM)));
            float sc = ac * frcp(n);
            float ux0 = (l == 0) ? 0.f : sc * a[p].x;
            float uy = sc * a[p].y, uz = sc * a[p].z, uw = sc * a[p].w;
            unsigned short hx = f2bf(ux0), hy = f2bf(uy), hz = f2bf(uz), hw = f2bf(uw);
            ushort4 hv = {hx, hy, hz, hw};
            ushort4 lv = {f2bf(ux0 - bf2f(hx)), f2bf(uy - bf2f(hy)),
                          f2bf(uz - bf2f(hz)), f2bf(uw - bf2f(hw))};
            *(ushort4*)(uh + r * UPITCH + p * 64 + 4 * l) = hv;
            *(ushort4*)(ul + r * UPITCH + p * 64 + 4 * l) = lv;
        }
    }
    __syncthreads();  // the only barrier

    // ---- MFMA GEMM: M=16, N=256 (wave wv: 4 n-tiles), K=256, split-bf16 3-term ----
    float4v acc[4];
#pragma unroll
    for (int j = 0; j < 4; j++) acc[j] = (float4v){0.f, 0.f, 0.f, 0.f};
    int abyte = (lane & 15) * (UPITCH * 2) + (lane >> 4) * 16;
#pragma unroll
    for (int ks = 0; ks < 8; ks++) {
        short8v Ah = *(const short8v*)(smem + abyte + ks * 64);
        short8v Al = *(const short8v*)(smem + 8448 + abyte + ks * 64);
#pragma unroll
        for (int j = 0; j < 4; j++) {
            size_t chunk = ((size_t)((wv * 4 + j) * 8 + ks) * 64 + lane) * 8;
            short8v Bh = *(const short8v*)(bhi + chunk);
            short8v Bl = *(const short8v*)(blo + chunk);
            acc[j] = __builtin_amdgcn_mfma_f32_16x16x32_bf16(Ah, Bh, acc[j], 0, 0, 0);
            acc[j] = __builtin_amdgcn_mfma_f32_16x16x32_bf16(Al, Bh, acc[j], 0, 0, 0);
            acc[j] = __builtin_amdgcn_mfma_f32_16x16x32_bf16(Ah, Bl, acc[j], 0, 0, 0);
        }
    }

    // ---- epilogue directly from accumulators ----
    // D layout: col = (wv*4+j)*16 + (lane&15), row = (lane>>4)*4 + reg
    int lp = lane & 15, hi = lane >> 4;
    float uf[4];
#pragma unroll
    for (int j = 0; j < 4; j++) uf[j] = uspL[wv * 64 + j * 16 + lp];
    if (lp == 0) {  // mask the point's time element (global col d=0 -> j==0, lp==0)
        acc[0][0] = 0.f; acc[0][1] = 0.f; acc[0][2] = 0.f; acc[0][3] = 0.f;
    }
    float n2v[4], duv[4];
#pragma unroll
    for (int reg = 0; reg < 4; reg++) {
        float pn = 0.f, pd = 0.f;
#pragma unroll
        for (int j = 0; j < 4; j++) {
            pn = fmaf(acc[j][reg], acc[j][reg], pn);
            pd = fmaf(acc[j][reg], uf[j], pd);
        }
        n2v[reg] = pn; duv[reg] = pd;
    }
#pragma unroll
    for (int off = 1; off < 16; off <<= 1) {
#pragma unroll
        for (int reg = 0; reg < 4; reg++) {
            n2v[reg] += __shfl_xor(n2v[reg], off, 64);
            duv[reg] += __shfl_xor(duv[reg], off, 64);
        }
    }
    float U2 = u2L[wv];

    float A[4], Bc[4];
#pragma unroll
    for (int reg = 0; reg < 4; reg++) {
        float n2 = n2v[reg], duu = duv[reg];
        float n = fmaxf(sqrtf(n2), MIN_NORM);
        float epv = __expf(n), emv = frcp(epv);
        float sv = 0.5f * (epv - emv) * frcp(n);     // sinh(n)/n
        float hs2 = sv * sv * n2;
        float h0 = sqrtf(fmaxf(1.f + hs2, EPS));
        float yn = fmaxf(sv * n, MIN_NORM);
        float dhu = sv * duu;
        float alpha = dhu * frcp(yn);
        float g = alpha * (1.f - h0);
        float ux = dhu - g * yn;
        float t = ux * frcp(fmaxf(h0, MIN_NORM));
        float w2 = U2 - 2.f * g * alpha + g * g;
        float md = w2 - t * t;
        float normu = fminf(sqrtf(fmaxf(md, EPS)), MAX_NORM);
        float theta = fmaxf(normu, MIN_NORM);
        float ep2 = __expf(theta), em2 = frcp(ep2);
        float ch = 0.5f * (ep2 + em2);
        float shot = 0.5f * (ep2 - em2) * frcp(theta);
        float rn2 = ch * ch * hs2 + 2.f * ch * shot * ux + shot * shot * w2;
        float rtime = sqrtf(fmaxf(1.f + rn2, EPS));
        float th2 = fmaxf(rtime, 1.f + EPS);
        float ac2 = __logf(th2 + sqrtf(fmaxf(th2 * th2 - 1.f, MIN_NORM)));
        float rn = fmaxf(sqrtf(rn2), MIN_NORM);
        float K = ac2 * frcp(rn);
        A[reg] = K * sv * (ch - shot * g * frcp(yn));
        Bc[reg] = K * shot;
    }

    unsigned short* xbase = xt + (size_t)(row0 + hi * 4) * 256 + wv * 64 + lp;
#pragma unroll
    for (int reg = 0; reg < 4; reg++) {
#pragma unroll
        for (int j = 0; j < 4; j++) {
            float o = fmaf(A[reg], acc[j][reg], Bc[reg] * uf[j]);
            xbase[reg * 256 + j * 16] = f2bf(o);
        }
    }
}

// ---------- scan (single block, int4 loads) ----------
#define SCH 32
__global__ __launch_bounds__(1024) void scan_kernel(const int* __restrict__ counts,
                                                    int* __restrict__ starts, int n) {
    int tid = threadIdx.x, lane = tid & 63, wv = tid >> 6;
    int i0 = tid * SCH;
    int c[SCH];
    const int4* c4 = (const int4*)(counts + i0);
#pragma unroll
    for (int q = 0; q < 8; q++) {
        int4 v = c4[q];   // reads past n land in zeroed cursor region (safe, zero)
        c[4 * q] = v.x; c[4 * q + 1] = v.y; c[4 * q + 2] = v.z; c[4 * q + 3] = v.w;
    }
    int s = 0;
#pragma unroll
    for (int j = 0; j < SCH; j++) s += c[j];
    int incl = s;
#pragma unroll
    for (int off = 1; off < 64; off <<= 1) {
        int t = __shfl_up(incl, off, 64);
        if (lane >= off) incl += t;
    }
    __shared__ int wtot[16];
    if (lane == 63) wtot[wv] = incl;
    __syncthreads();
    if (wv == 0 && lane < 16) {
        int v = wtot[lane];
        int sc = v;
#pragma unroll
        for (int off = 1; off < 16; off <<= 1) {
            int t = __shfl_up(sc, off, 64);
            if (lane >= off) sc += t;
        }
        wtot[lane] = sc - v;  // exclusive
    }
    __syncthreads();
    int run = incl - s + wtot[wv];
#pragma unroll
    for (int j = 0; j < SCH; j++) {
        int idx = i0 + j;
        if (idx < n) starts[idx] = run;
        run += c[j];
    }
    if (tid == 1023) starts[n] = run;
}

// ---------- scatter: packed (col, val) per edge ----------
__global__ void scatter_kernel(const int* __restrict__ row, const int* __restrict__ col,
                               const float* __restrict__ val, const int* __restrict__ starts,
                               int* __restrict__ cursor, int2* __restrict__ ep, int E) {
    int e = blockIdx.x * 256 + threadIdx.x;
    if (e < E) {
        int r = row[e];
        int pos = starts[r] + atomicAdd(&cursor[r], 1);
        ep[pos] = make_int2(col[e], __float_as_int(val[e]));
    }
}

// ---------- SpMM (wave/row, predicated 8-wide batches) + fused final chain ----------
__global__ __launch_bounds__(256) void spmm_final_kernel(const unsigned short* __restrict__ xt,
                                                         const int2* __restrict__ ep,
                                                         const int* __restrict__ starts,
                                                         float4* __restrict__ out4) {
    int w = threadIdx.x >> 6;
    int lane = threadIdx.x & 63;
    int r = blockIdx.x * 4 + w;
    int s = starts[r], e = starts[r + 1];

    float4 acc = {0.f, 0.f, 0.f, 0.f};
    for (int i = s; i < e; i += 8) {
        int cs[8]; float vs[8];
#pragma unroll
        for (int u = 0; u < 8; u++) {
            int idx = i + u;
            bool ok = idx < e;
            int2 pe = ep[ok ? idx : s];
            cs[u] = pe.x;
            vs[u] = ok ? __int_as_float(pe.y) : 0.f;
        }
        ushort4 av[8];
#pragma unroll
        for (int u = 0; u < 8; u++)
            av[u] = *(const ushort4*)(xt + ((size_t)cs[u] << 8) + (lane << 2));
#pragma unroll
        for (int u = 0; u < 8; u++) {
            acc.x = fmaf(vs[u], bf2f(av[u].x), acc.x);
            acc.y = fmaf(vs[u], bf2f(av[u].y), acc.y);
            acc.z = fmaf(vs[u], bf2f(av[u].z), acc.z);
            acc.w = fmaf(vs[u], bf2f(av[u].w), acc.w);
        }
    }

    acc.x = fminf(acc.x, MAX_NORM); acc.y = fminf(acc.y, MAX_NORM);
    acc.z = fminf(acc.z, MAX_NORM); acc.w = fminf(acc.w, MAX_NORM);

    // final chain: expmap0+proj -> logmap0 -> relu/clamp -> expmap0+proj
    bool leader = ((lane & 15) == 0);
    float4 sp = acc;
    if (leader) sp.x = 0.f;
    float n2 = gsum16(sp.x * sp.x + sp.y * sp.y + sp.z * sp.z + sp.w * sp.w);
    float n = fmaxf(sqrtf(n2), MIN_NORM);
    float ep1 = __expf(n), em1 = frcp(ep1);
    float s1 = 0.5f * (ep1 - em1) * frcp(n);
    float hs2 = s1 * s1 * n2;
    float time = sqrtf(fmaxf(1.f + hs2, EPS));
    float th = fmaxf(time, 1.f + EPS);
    float ac = __logf(th + sqrtf(fmaxf(th * th - 1.f, MIN_NORM)));
    float hn = fmaxf(s1 * n, MIN_NORM);
    float sc = ac * s1 * frcp(hn);
    float4 t;
    t.x = leader ? 0.f : sc * sp.x;
    t.y = sc * sp.y;
    t.z = sc * sp.z;
    t.w = sc * sp.w;
    t.x = fminf(fmaxf(t.x, 0.f), MAX_NORM);
    t.y = fminf(fmaxf(t.y, 0.f), MAX_NORM);
    t.z = fminf(fmaxf(t.z, 0.f), MAX_NORM);
    t.w = fminf(fmaxf(t.w, 0.f), MAX_NORM);
    float t2 = gsum16(t.x * t.x + t.y * t.y + t.z * t.z + t.w * t.w);
    float nt = fmaxf(sqrtf(t2), MIN_NORM);
    float ep3 = __expf(nt), em3 = frcp(ep3);
    float s3 = 0.5f * (ep3 - em3) * frcp(nt);
    float time3 = sqrtf(fmaxf(1.f + s3 * s3 * t2, EPS));
    float4 o;
    o.x = leader ? time3 : s3 * t.x;
    o.y = s3 * t.y;
    o.z = s3 * t.z;
    o.w = s3 * t.w;

    out4[(size_t)r * 64 + lane] = o;
}

extern "C" void kernel_launch(void* const* d_in, const int* in_sizes, int n_in,
                              void* d_out, int out_size, void* d_ws, size_t ws_size,
                              hipStream_t stream) {
    const float* x       = (const float*)d_in[0];
    const float* adj_val = (const float*)d_in[1];
    const float* weight  = (const float*)d_in[2];
    const float* bias    = (const float*)d_in[3];
    const int*   adj_row = (const int*)d_in[4];
    const int*   adj_col = (const int*)d_in[5];

    const int N = NN, E = EE;

    unsigned short* B   = (unsigned short*)d_ws;          // N*256 bf16 (xt)
    unsigned short* Whi = B + (size_t)N * 256;            // 65536 ushort
    unsigned short* Wlo = Whi + 65536;                    // 65536 ushort
    int* counts  = (int*)(Wlo + 65536);                   // N   (16B-aligned)
    int* cursor  = counts + N;                            // N
    int* starts  = cursor + N;                            // N+1 (+1 pad for int2 align)
    int2* ep     = (int2*)(starts + N + 2);               // E   (8B-aligned)

    hipMemsetAsync(counts, 0, 2 * N * sizeof(int), stream);
    prep_kernel<<<32, 256, 0, stream>>>(weight, Whi, Wlo);
    fused_front_hist_kernel<<<N / GR, 256, 0, stream>>>(x, Whi, Wlo, bias, B,
                                                        adj_row, counts);
    scan_kernel<<<1, 1024, 0, stream>>>(counts, starts, N);
    scatter_kernel<<<(E + 255) / 256, 256, 0, stream>>>(adj_row, adj_col, adj_val,
                                                        starts, cursor, ep, E);
    spmm_final_kernel<<<N / 4, 256, 0, stream>>>(B, ep, starts, (float4*)d_out);
}